// Round 3
// baseline (544.854 us; speedup 1.0000x reference)
//
#include <hip/hip_runtime.h>

// Problem constants
#define NN 4096   // nodes
#define KK 48     // neighbors
#define CC 128    // channels
#define EC 384    // edge context
#define DD 512    // CC + ECTX
#define HH 512    // dense hidden

typedef short bf16x8 __attribute__((ext_vector_type(8)));
typedef float f32x4 __attribute__((ext_vector_type(4)));

// hardware packed fp32->bf16 (RNE), 1 instr per 2 elements
__device__ __forceinline__ unsigned int pk2(float lo, float hi){
  unsigned int r;
  asm("v_cvt_pk_bf16_f32 %0, %1, %2" : "=v"(r) : "v"(lo), "v"(hi));
  return r;
}
__device__ __forceinline__ unsigned short f2bf(float x){
  return (unsigned short)pk2(x, x);
}
__device__ __forceinline__ bf16x8 pack8(f32x4 a, f32x4 b){
  union { unsigned int w[4]; bf16x8 v; } u;
  u.w[0]=pk2(a[0],a[1]); u.w[1]=pk2(a[2],a[3]);
  u.w[2]=pk2(b[0],b[1]); u.w[3]=pk2(b[2],b[3]);
  return u.v;
}

// tanh-form gelu via hardware exp: |err vs exact erf-gelu| ~1e-3
__device__ __forceinline__ float gelu_f(float x){
  float s = 1.5957691216057308f * (x + 0.044715f*x*x*x);
  float e = __expf(s);
  float t = 1.0f - 2.0f/(e + 1.0f);
  return 0.5f*x*(1.0f + t);
}

// ---------------- weight fp32 -> bf16 conversion ---------------------------------
__global__ void cvt_kernel(const float* __restrict__ W1, const float* __restrict__ W2,
                           const float* __restrict__ W3, const float* __restrict__ Wd1,
                           const float* __restrict__ Wd2, unsigned short* __restrict__ o){
  int i = blockIdx.x*256 + threadIdx.x;   // grid 896*256 = 229376
  float v;
  if      (i <  65536) v = W1[i];
  else if (i <  81920) v = W2[i-65536];
  else if (i <  98304) v = W3[i-81920];
  else if (i < 163840) v = Wd1[i-98304];
  else                 v = Wd2[i-163840];
  o[i] = f2bf(v);
}

// ---------------- node-part hoist: Y = nodef @ W1_node^T + b1 (4096x128) ---------
// 64 blocks x 256 thr; block = 64 rows; wave = 16 rows x 128 cols
__global__ __launch_bounds__(256, 4) void node_kernel(
    const float* __restrict__ nodef, const unsigned short* __restrict__ W1b,
    const float* __restrict__ b1, float* __restrict__ Y)
{
  const int tid  = threadIdx.x;
  const int lane = tid & 63;
  const int wid  = tid >> 6;
  const int l15  = lane & 15;
  const int lg   = lane >> 4;
  const int lg8  = lg*8;
  const int rowb = blockIdx.x*64 + wid*16;

  f32x4 acc[8];
  #pragma unroll
  for (int nt=0; nt<8; ++nt) acc[nt] = (f32x4){0.f,0.f,0.f,0.f};

  const float* arow = nodef + (size_t)(rowb + l15)*CC;
  #pragma unroll
  for (int ks=0; ks<4; ++ks){
    const int k0 = ks*32;
    bf16x8 af = pack8(*(const f32x4*)(arow + k0 + lg8), *(const f32x4*)(arow + k0 + lg8 + 4));
    #pragma unroll
    for (int nt=0; nt<8; ++nt){
      bf16x8 bf_ = *(const bf16x8*)(W1b + (size_t)(nt*16 + l15)*DD + k0 + lg8);
      acc[nt] = __builtin_amdgcn_mfma_f32_16x16x32_bf16(af, bf_, acc[nt], 0,0,0);
    }
  }
  #pragma unroll
  for (int nt=0; nt<8; ++nt){
    const int c = nt*16 + l15;
    const float bb = b1[c];
    #pragma unroll
    for (int j=0; j<4; ++j)
      Y[(size_t)(rowb + lg*4 + j)*CC + c] = acc[nt][j] + bb;
  }
}

// ---------------- message MLP + aggregation -------------------------------------
// block = 256 threads (4 waves: 2 M-waves x 2 N-waves), 2 nodes (96 edge rows)
// GEMM1 K-loop covers ONLY the edge part (K=384); node part comes in via Y.
__global__ __launch_bounds__(256, 4) void msg_kernel(
    const float* __restrict__ nodef, const float* __restrict__ edgef,
    const float* __restrict__ attn, const float* __restrict__ Y,
    const unsigned short* __restrict__ W1b,
    const unsigned short* __restrict__ W2b, const float* __restrict__ b2,
    const unsigned short* __restrict__ W3b, const float* __restrict__ b3,
    float* __restrict__ x1)
{
  __shared__ __attribute__((aligned(16))) unsigned short H[96][136]; // reused H1 then H2

  const int tid  = threadIdx.x;
  const int lane = tid & 63;
  const int wid  = tid >> 6;
  const int wm   = wid & 1;       // M-half (node within block)
  const int wn   = wid >> 1;      // N-half (64 cols)
  const int l15  = lane & 15;
  const int lg   = lane >> 4;     // 0..3
  const int lg8  = lg*8;
  const int node = blockIdx.x*2 + wm;
  const int colb = wn*64;

  const float* erow[3];
  #pragma unroll
  for (int mt=0; mt<3; ++mt)
    erow[mt] = edgef + ((size_t)node*KK + (mt*16 + l15))*EC;

  // acc init = Y[node][col]  (same value for every edge row j / mt)
  float yv[4];
  #pragma unroll
  for (int nt=0; nt<4; ++nt)
    yv[nt] = Y[(size_t)node*CC + colb + nt*16 + l15];

  f32x4 acc[3][4];
  #pragma unroll
  for (int mt=0; mt<3; ++mt)
    #pragma unroll
    for (int nt=0; nt<4; ++nt)
      #pragma unroll
      for (int j=0; j<4; ++j) acc[mt][nt][j] = yv[nt];

  // ---- GEMM1 (edge part, K=384): A direct-from-global fp32 -> cvt_pk bf16 ------
  bf16x8 aC[3], bC[4], aN[3], bN[4];
  #pragma unroll
  for (int nt=0; nt<4; ++nt)
    bC[nt] = *(const bf16x8*)(W1b + (size_t)(colb + nt*16 + l15)*DD + CC + lg8);
  #pragma unroll
  for (int mt=0; mt<3; ++mt)
    aC[mt] = pack8(*(const f32x4*)(erow[mt] + lg8), *(const f32x4*)(erow[mt] + lg8 + 4));

  #pragma unroll
  for (int ks=0; ks<12; ++ks){
    if (ks < 11){
      const int k1 = (ks+1)*32;
      #pragma unroll
      for (int nt=0; nt<4; ++nt)
        bN[nt] = *(const bf16x8*)(W1b + (size_t)(colb + nt*16 + l15)*DD + CC + k1 + lg8);
      #pragma unroll
      for (int mt=0; mt<3; ++mt)
        aN[mt] = pack8(*(const f32x4*)(erow[mt] + k1 + lg8), *(const f32x4*)(erow[mt] + k1 + lg8 + 4));
    }
    #pragma unroll
    for (int mt=0; mt<3; ++mt)
      #pragma unroll
      for (int nt=0; nt<4; ++nt)
        acc[mt][nt] = __builtin_amdgcn_mfma_f32_16x16x32_bf16(aC[mt], bC[nt], acc[mt][nt], 0,0,0);
    #pragma unroll
    for (int mt=0; mt<3; ++mt) aC[mt] = aN[mt];
    #pragma unroll
    for (int nt=0; nt<4; ++nt) bC[nt] = bN[nt];
  }

  // epilogue 1: gelu (b1 already folded into Y), -> H (bf16)
  #pragma unroll
  for (int nt=0; nt<4; ++nt){
    const int c = colb + nt*16 + l15;
    #pragma unroll
    for (int mt=0; mt<3; ++mt){
      const int r0 = wm*48 + mt*16 + lg*4;
      #pragma unroll
      for (int j=0; j<4; ++j)
        H[r0+j][c] = f2bf(gelu_f(acc[mt][nt][j]));
    }
  }
  __syncthreads();

  // ---- GEMM2: (96x128) x W2^T, A from LDS ----
  f32x4 a2[3][4];
  #pragma unroll
  for (int mt=0; mt<3; ++mt)
    #pragma unroll
    for (int nt=0; nt<4; ++nt) a2[mt][nt] = (f32x4){0.f,0.f,0.f,0.f};

  #pragma unroll
  for (int ks=0; ks<4; ++ks){
    const int k0 = ks*32;
    bf16x8 bf_[4], af_[3];
    #pragma unroll
    for (int nt=0; nt<4; ++nt)
      bf_[nt] = *(const bf16x8*)(W2b + (size_t)(colb + nt*16 + l15)*CC + k0 + lg8);
    #pragma unroll
    for (int mt=0; mt<3; ++mt)
      af_[mt] = *(const bf16x8*)&H[wm*48 + mt*16 + l15][k0 + lg8];
    #pragma unroll
    for (int mt=0; mt<3; ++mt)
      #pragma unroll
      for (int nt=0; nt<4; ++nt)
        a2[mt][nt] = __builtin_amdgcn_mfma_f32_16x16x32_bf16(af_[mt], bf_[nt], a2[mt][nt], 0,0,0);
  }
  __syncthreads();   // all GEMM2 reads done before H is overwritten

  #pragma unroll
  for (int nt=0; nt<4; ++nt){
    const int c = colb + nt*16 + l15;
    const float bb = b2[c];
    #pragma unroll
    for (int mt=0; mt<3; ++mt){
      const int r0 = wm*48 + mt*16 + lg*4;
      #pragma unroll
      for (int j=0; j<4; ++j)
        H[r0+j][c] = f2bf(gelu_f(a2[mt][nt][j] + bb));
    }
  }
  __syncthreads();

  // ---- GEMM3: (96x128) x W3^T (linear out) ----
  f32x4 a3[3][4];
  #pragma unroll
  for (int mt=0; mt<3; ++mt)
    #pragma unroll
    for (int nt=0; nt<4; ++nt) a3[mt][nt] = (f32x4){0.f,0.f,0.f,0.f};

  #pragma unroll
  for (int ks=0; ks<4; ++ks){
    const int k0 = ks*32;
    bf16x8 bf_[4], af_[3];
    #pragma unroll
    for (int nt=0; nt<4; ++nt)
      bf_[nt] = *(const bf16x8*)(W3b + (size_t)(colb + nt*16 + l15)*CC + k0 + lg8);
    #pragma unroll
    for (int mt=0; mt<3; ++mt)
      af_[mt] = *(const bf16x8*)&H[wm*48 + mt*16 + l15][k0 + lg8];
    #pragma unroll
    for (int mt=0; mt<3; ++mt)
      #pragma unroll
      for (int nt=0; nt<4; ++nt)
        a3[mt][nt] = __builtin_amdgcn_mfma_f32_16x16x32_bf16(af_[mt], bf_[nt], a3[mt][nt], 0,0,0);
  }

  // aggregation: rows of this wave's frags all belong to `node`; cols disjoint per wave.
  float av[3][4];
  #pragma unroll
  for (int mt=0; mt<3; ++mt)
    #pragma unroll
    for (int j=0; j<4; ++j)
      av[mt][j] = attn[(size_t)node*KK + mt*16 + lg*4 + j];

  #pragma unroll
  for (int nt=0; nt<4; ++nt){
    const int c = colb + nt*16 + l15;
    const float bb = b3[c];
    float t = 0.f;
    #pragma unroll
    for (int mt=0; mt<3; ++mt)
      #pragma unroll
      for (int j=0; j<4; ++j)
        t += (a3[mt][nt][j] + bb) * av[mt][j];
    t += __shfl_xor(t, 16, 64);   // sum over the 4 row-groups
    t += __shfl_xor(t, 32, 64);
    if (lg == 0)
      x1[(size_t)node*CC + c] = nodef[(size_t)node*CC + c] + t*(1.0f/30.0f);
  }
}

// ---------------- LN1 -> dense MLP -> residual -> LN2 -> mask -------------------
// block = 256 threads (4 waves), 16 nodes
__global__ __launch_bounds__(256, 2) void post_kernel(
    const float* __restrict__ x1, const float* __restrict__ mask,
    const float* __restrict__ g1, const float* __restrict__ be1,
    const unsigned short* __restrict__ Wd1b, const float* __restrict__ bd1,
    const unsigned short* __restrict__ Wd2b, const float* __restrict__ bd2,
    const float* __restrict__ g2, const float* __restrict__ be2,
    float* __restrict__ out)
{
  __shared__ __attribute__((aligned(16))) unsigned short xlnB[16][136];
  __shared__ __attribute__((aligned(16))) float          xlnF[16][132];
  __shared__ __attribute__((aligned(16))) unsigned short Hb[16][520];
  __shared__ __attribute__((aligned(16))) float          x2s[16][132];

  const int tid  = threadIdx.x;
  const int lane = tid & 63;
  const int wid  = tid >> 6;
  const int l15  = lane & 15;
  const int lg   = lane >> 4;
  const int lg8  = lg*8;
  const int n0   = blockIdx.x * 16;

  // ---- LN1: 16 threads per node ----
  {
    const int nl = tid >> 4;
    const int s  = tid & 15;
    const float* row = x1 + (size_t)(n0+nl)*CC + s*8;
    f32x4 a = *(const f32x4*)row;
    f32x4 b = *(const f32x4*)(row+4);
    float sm = (a[0]+a[1])+(a[2]+a[3]) + (b[0]+b[1])+(b[2]+b[3]);
    float sq = a[0]*a[0]+a[1]*a[1]+a[2]*a[2]+a[3]*a[3]
             + b[0]*b[0]+b[1]*b[1]+b[2]*b[2]+b[3]*b[3];
    sm += __shfl_xor(sm,1,64); sq += __shfl_xor(sq,1,64);
    sm += __shfl_xor(sm,2,64); sq += __shfl_xor(sq,2,64);
    sm += __shfl_xor(sm,4,64); sq += __shfl_xor(sq,4,64);
    sm += __shfl_xor(sm,8,64); sq += __shfl_xor(sq,8,64);
    const float mu = sm*(1.f/128.f);
    const float rs = rsqrtf(sq*(1.f/128.f) - mu*mu + 1e-5f);
    #pragma unroll
    for (int j=0; j<8; ++j){
      const int c = s*8+j;
      float xv = (j<4) ? a[j] : b[j-4];
      float y = (xv-mu)*rs*g1[c] + be1[c];
      xlnF[nl][c] = y;
      xlnB[nl][c] = f2bf(y);
    }
  }
  __syncthreads();

  // ---- dense layer 1: (16x128) @ Wd1^T -> 16x512, gelu ----
  f32x4 a1[8];
  #pragma unroll
  for (int nt=0; nt<8; ++nt) a1[nt] = (f32x4){0.f,0.f,0.f,0.f};
  #pragma unroll
  for (int ks=0; ks<4; ++ks){
    const int k0 = ks*32;
    bf16x8 af = *(const bf16x8*)&xlnB[l15][k0 + lg8];
    #pragma unroll
    for (int nt=0; nt<8; ++nt){
      const int h = wid*128 + nt*16 + l15;
      bf16x8 bf_ = *(const bf16x8*)(Wd1b + (size_t)h*CC + k0 + lg8);
      a1[nt] = __builtin_amdgcn_mfma_f32_16x16x32_bf16(af, bf_, a1[nt], 0,0,0);
    }
  }
  #pragma unroll
  for (int nt=0; nt<8; ++nt){
    const int h = wid*128 + nt*16 + l15;
    const float bb = bd1[h];
    #pragma unroll
    for (int j=0; j<4; ++j)
      Hb[lg*4+j][h] = f2bf(gelu_f(a1[nt][j] + bb));
  }
  __syncthreads();

  // ---- dense layer 2: (16x512) @ Wd2^T -> 16x128, + residual ----
  f32x4 a2[2];
  #pragma unroll
  for (int nt=0; nt<2; ++nt) a2[nt] = (f32x4){0.f,0.f,0.f,0.f};
  #pragma unroll
  for (int ks=0; ks<16; ++ks){
    const int k0 = ks*32;
    bf16x8 af = *(const bf16x8*)&Hb[l15][k0 + lg8];
    #pragma unroll
    for (int nt=0; nt<2; ++nt){
      const int c = wid*32 + nt*16 + l15;
      bf16x8 bf_ = *(const bf16x8*)(Wd2b + (size_t)c*HH + k0 + lg8);
      a2[nt] = __builtin_amdgcn_mfma_f32_16x16x32_bf16(af, bf_, a2[nt], 0,0,0);
    }
  }
  #pragma unroll
  for (int nt=0; nt<2; ++nt){
    const int c = wid*32 + nt*16 + l15;
    const float bb = bd2[c];
    #pragma unroll
    for (int j=0; j<4; ++j){
      const int r = lg*4 + j;
      x2s[r][c] = xlnF[r][c] + a2[nt][j] + bb;
    }
  }
  __syncthreads();

  // ---- LN2 + mask + store ----
  {
    const int nl = tid >> 4;
    const int s  = tid & 15;
    float xv[8];
    float sm = 0.f, sq = 0.f;
    #pragma unroll
    for (int j=0; j<8; ++j){ xv[j] = x2s[nl][s*8+j]; sm += xv[j]; sq += xv[j]*xv[j]; }
    sm += __shfl_xor(sm,1,64); sq += __shfl_xor(sq,1,64);
    sm += __shfl_xor(sm,2,64); sq += __shfl_xor(sq,2,64);
    sm += __shfl_xor(sm,4,64); sq += __shfl_xor(sq,4,64);
    sm += __shfl_xor(sm,8,64); sq += __shfl_xor(sq,8,64);
    const float mu = sm*(1.f/128.f);
    const float rs = rsqrtf(sq*(1.f/128.f) - mu*mu + 1e-5f);
    const float mk = mask[n0+nl];
    f32x4 o0, o1;
    #pragma unroll
    for (int j=0; j<8; ++j){
      const int c = s*8+j;
      float y = (xv[j]-mu)*rs*g2[c] + be2[c];
      if (j < 4) o0[j] = mk*y; else o1[j-4] = mk*y;
    }
    float* orow = out + (size_t)(n0+nl)*CC + s*8;
    *(f32x4*)orow     = o0;
    *(f32x4*)(orow+4) = o1;
  }
}

extern "C" void kernel_launch(void* const* d_in, const int* in_sizes, int n_in,
                              void* d_out, int out_size, void* d_ws, size_t ws_size,
                              hipStream_t stream)
{
  (void)in_sizes; (void)n_in; (void)out_size; (void)ws_size;

  const float* nodef = (const float*)d_in[0];
  const float* edgef = (const float*)d_in[1];
  const float* mask  = (const float*)d_in[2];
  const float* attn  = (const float*)d_in[3];
  const float* W_m1  = (const float*)d_in[4];
  const float* b_m1  = (const float*)d_in[5];
  const float* W_m2  = (const float*)d_in[6];
  const float* b_m2  = (const float*)d_in[7];
  const float* W_m3  = (const float*)d_in[8];
  const float* b_m3  = (const float*)d_in[9];
  const float* g1    = (const float*)d_in[10];
  const float* be1   = (const float*)d_in[11];
  const float* W_d1  = (const float*)d_in[12];
  const float* b_d1  = (const float*)d_in[13];
  const float* W_d2  = (const float*)d_in[14];
  const float* b_d2  = (const float*)d_in[15];
  const float* g2    = (const float*)d_in[16];
  const float* be2   = (const float*)d_in[17];

  // ws layout: [0, 458752) bf16 weights; [458752, 2555904) x1 f32;
  //            [2555904, 4653056) Y f32
  unsigned short* wsb  = (unsigned short*)d_ws;
  unsigned short* W1b  = wsb;
  unsigned short* W2b  = wsb + 65536;
  unsigned short* W3b  = wsb + 81920;
  unsigned short* Wd1b = wsb + 98304;
  unsigned short* Wd2b = wsb + 163840;
  float* x1 = (float*)((char*)d_ws + 458752);
  float* Y  = (float*)((char*)d_ws + 2555904);

  cvt_kernel<<<896, 256, 0, stream>>>(W_m1, W_m2, W_m3, W_d1, W_d2, wsb);
  node_kernel<<<64, 256, 0, stream>>>(nodef, W1b, b_m1, Y);
  msg_kernel<<<2048, 256, 0, stream>>>(nodef, edgef, attn, Y,
                                       W1b, W2b, b_m2, W3b, b_m3, x1);
  post_kernel<<<256, 256, 0, stream>>>(x1, mask, g1, be1, Wd1b, b_d1,
                                       Wd2b, b_d2, g2, be2, (float*)d_out);
}